// Round 4
// baseline (2497.150 us; speedup 1.0000x reference)
//
#include <hip/hip_runtime.h>
#include <math.h>

// Markowitz min-variance via FISTA, one block (512 thr, 8 waves) per problem.
// Q register-resident: thread (r4=tid&63, e=tid>>6) owns Q[4*r4..+3][32*e..+31].
// R6 (on R5's wave0-serial structure, 905us):
//  - g-reduction via LDS float atomics (ds_add_f32): waves atomicAdd partials
//    into a 256-float buffer -> wave0 reads ONE float4 instead of 8 + 28 adds.
//    Double-buffered; wave1 re-zeros the idle buffer during wave0's serial
//    window. Ping-pong safety: buffer p is read by wave0 in window k (parity p),
//    re-zeroed by wave1 in window k+1 (parity p^1, after B2 -> ordered after
//    wave0's read by B1(k+1)), re-used for atomics in window k+2 (after B1 ->
//    ordered after the zeroing). No race.
//  - frozen-w exit threshold 1e-10 -> 1e-7 (window-max over 8 iters). Bound:
//    remaining reference movement <= 300*1e-7 = 3e-5 << tolerance.
//  - Newton tol 5e-5 -> 1e-4 (tau err <= tol/cnt ~ 1e-6; exact final step fixes)
//  - y published before frozen-bookkeeping tail (earlier B1 handoff)

#define NA    256
#define CAPW  0.05f

typedef float v2f __attribute__((ext_vector_type(2)));

// ---- DPP wave-64 reductions ----
template<int CTRL, int RM>
__device__ __forceinline__ float dpp0(float x) {      // old = 0, bound_ctrl = true
    return __int_as_float(__builtin_amdgcn_update_dpp(
        0, __float_as_int(x), CTRL, RM, 0xf, true));
}
template<int CTRL, int RM>
__device__ __forceinline__ float dppI(float x, float ident) { // old = ident
    return __int_as_float(__builtin_amdgcn_update_dpp(
        __float_as_int(ident), __float_as_int(x), CTRL, RM, 0xf, false));
}
__device__ __forceinline__ float bcast63(float x) {
    return __int_as_float(__builtin_amdgcn_readlane(__float_as_int(x), 63));
}
__device__ __forceinline__ float wsum(float x) {
    x += dpp0<0x111, 0xf>(x);   // row_shr:1
    x += dpp0<0x112, 0xf>(x);   // row_shr:2
    x += dpp0<0x114, 0xf>(x);   // row_shr:4
    x += dpp0<0x118, 0xf>(x);   // row_shr:8
    x += dpp0<0x142, 0xa>(x);   // row_bcast:15 -> rows 1,3
    x += dpp0<0x143, 0xc>(x);   // row_bcast:31 -> rows 2,3
    return bcast63(x);
}
__device__ __forceinline__ float wmax(float x) {
    const float I = -1e30f;
    x = fmaxf(x, dppI<0x111, 0xf>(x, I));
    x = fmaxf(x, dppI<0x112, 0xf>(x, I));
    x = fmaxf(x, dppI<0x114, 0xf>(x, I));
    x = fmaxf(x, dppI<0x118, 0xf>(x, I));
    x = fmaxf(x, dppI<0x142, 0xa>(x, I));
    x = fmaxf(x, dppI<0x143, 0xc>(x, I));
    return bcast63(x);
}

__global__ void __launch_bounds__(512, 2)
markowitz_fista(const float* __restrict__ A, float* __restrict__ out)
{
    // 32KB pool: phase 1 uses all of it as A staging; afterwards:
    //   [0..255]   g buffer 0 (atomic-reduced matvec output)
    //   [256..511] g buffer 1
    //   [512..767] published y vector
    __shared__ float lds_pool[32 * 256];
    __shared__ int   done_flag;

    float* A_lds = lds_pool;
    float* gbuf0 = lds_pool;
    float* gbuf1 = lds_pool + 256;
    float* y_lds = lds_pool + 512;

    const int tid = threadIdx.x;
    const int b   = blockIdx.x;
    const int r4  = tid & 63;
    const int e   = tid >> 6;           // wave id == col-chunk
    const int R0  = r4 * 4;
    const int C0  = e * 32;

    const float* __restrict__ Ab = A + (size_t)b * NA * NA;

    // ---------------- Phase 1: Q = A^T A into registers (packed fp32) -------
    v2f q2[4][16];
    #pragma unroll
    for (int a = 0; a < 4; ++a)
        #pragma unroll
        for (int k = 0; k < 16; ++k) q2[a][k] = (v2f){0.0f, 0.0f};

    for (int it = 0; it < 8; ++it) {
        __syncthreads();
        const float4* src = (const float4*)(Ab + it * 32 * 256);
        float4* dst = (float4*)A_lds;
        #pragma unroll
        for (int qd = 0; qd < 4; ++qd) dst[qd * 512 + tid] = src[qd * 512 + tid];
        __syncthreads();
        for (int ii = 0; ii < 32; ++ii) {
            const float* row = A_lds + ii * 256;
            float4 rv = *(const float4*)(row + R0);
            v2f r0 = {rv.x, rv.x}, r1 = {rv.y, rv.y}, r2 = {rv.z, rv.z}, r3 = {rv.w, rv.w};
            #pragma unroll
            for (int cc = 0; cc < 8; ++cc) {
                float4 cv = *(const float4*)(row + C0 + 4 * cc);
                v2f clo = {cv.x, cv.y}, chi = {cv.z, cv.w};
                q2[0][2*cc  ] = __builtin_elementwise_fma(r0, clo, q2[0][2*cc  ]);
                q2[0][2*cc+1] = __builtin_elementwise_fma(r0, chi, q2[0][2*cc+1]);
                q2[1][2*cc  ] = __builtin_elementwise_fma(r1, clo, q2[1][2*cc  ]);
                q2[1][2*cc+1] = __builtin_elementwise_fma(r1, chi, q2[1][2*cc+1]);
                q2[2][2*cc  ] = __builtin_elementwise_fma(r2, clo, q2[2][2*cc  ]);
                q2[2][2*cc+1] = __builtin_elementwise_fma(r2, chi, q2[2][2*cc+1]);
                q2[3][2*cc  ] = __builtin_elementwise_fma(r3, clo, q2[3][2*cc  ]);
                q2[3][2*cc+1] = __builtin_elementwise_fma(r3, chi, q2[3][2*cc+1]);
            }
        }
    }
    __syncthreads();   // alias safety: all A_lds reads done before g/y reuse

    // zero both g buffers (floats 0..511 of the pool)
    if (tid < 128) {
        ((float4*)lds_pool)[tid] = make_float4(0.f, 0.f, 0.f, 0.f);
    }

    // all waves: atomic-accumulate partials of Q*y_lds into gbuf.
    // Returns true on early-exit (flag read hidden behind the matvec FMAs).
    auto partials = [&](float* gbuf, bool chk) -> bool {
        __syncthreads();                               // B1: y_lds/flag/zeroing visible
        int fl = chk ? done_flag : 0;
        v2f aL0 = {0,0}, aL1 = {0,0}, aL2 = {0,0}, aL3 = {0,0};
        v2f aH0 = {0,0}, aH1 = {0,0}, aH2 = {0,0}, aH3 = {0,0};
        const float* yv = y_lds + C0;
        #pragma unroll
        for (int cc = 0; cc < 8; ++cc) {
            float4 y4 = *(const float4*)(yv + 4 * cc);
            v2f ylo = {y4.x, y4.y}, yhi = {y4.z, y4.w};
            aL0 = __builtin_elementwise_fma(q2[0][2*cc  ], ylo, aL0);
            aH0 = __builtin_elementwise_fma(q2[0][2*cc+1], yhi, aH0);
            aL1 = __builtin_elementwise_fma(q2[1][2*cc  ], ylo, aL1);
            aH1 = __builtin_elementwise_fma(q2[1][2*cc+1], yhi, aH1);
            aL2 = __builtin_elementwise_fma(q2[2][2*cc  ], ylo, aL2);
            aH2 = __builtin_elementwise_fma(q2[2][2*cc+1], yhi, aH2);
            aL3 = __builtin_elementwise_fma(q2[3][2*cc  ], ylo, aL3);
            aH3 = __builtin_elementwise_fma(q2[3][2*cc+1], yhi, aH3);
        }
        if (fl) return true;                           // block-uniform
        v2f s0 = aL0 + aH0, s1 = aL1 + aH1, s2 = aL2 + aH2, s3 = aL3 + aH3;
        atomicAdd(&gbuf[R0 + 0], s0.x + s0.y);
        atomicAdd(&gbuf[R0 + 1], s1.x + s1.y);
        atomicAdd(&gbuf[R0 + 2], s2.x + s2.y);
        atomicAdd(&gbuf[R0 + 3], s3.x + s3.y);
        __syncthreads();                               // B2: gbuf complete
        return false;
    };

    float* gb[2] = { gbuf0, gbuf1 };
    int pp = 0;

    // ---------------- Phase 2: power iteration for step size ----------------
    if (tid < 64) {
        *(float4*)(y_lds + 4 * tid) = make_float4(0.0625f, 0.0625f, 0.0625f, 0.0625f);
    }
    float u0 = 0.f, u1 = 0.f, u2 = 0.f, u3 = 0.f;
    for (int p = 0; p < 30; ++p) {
        partials(gb[pp], false);
        if (tid < 64) {
            float4 g4 = *(const float4*)(gb[pp] + 4 * tid);
            float ss = wsum(g4.x*g4.x + g4.y*g4.y + g4.z*g4.z + g4.w*g4.w);
            float inv = 1.0f / (sqrtf(ss) + 1e-12f);
            u0 = g4.x * inv; u1 = g4.y * inv; u2 = g4.z * inv; u3 = g4.w * inv;
            *(float4*)(y_lds + 4 * tid) = make_float4(u0, u1, u2, u3);
        } else if (tid < 128) {   // wave1: re-zero the idle buffer
            *(float4*)(gb[pp ^ 1] + 4 * (tid - 64)) = make_float4(0.f, 0.f, 0.f, 0.f);
        }
        pp ^= 1;
    }
    partials(gb[pp], false);   // Q*u for Rayleigh quotient

    float step2 = 0.f, t = 1.0f, tau_ws = 0.0f, tau_pv = 0.0f, rm = 0.0f;
    float wa = 0.f, wb = 0.f, wc = 0.f, wd = 0.f;
    float ya = 0.f, yb = 0.f, yc = 0.f, yd = 0.f;
    if (tid < 64) {
        float4 g4 = *(const float4*)(gb[pp] + 4 * tid);
        float lm = wsum(u0*g4.x + u1*g4.y + u2*g4.z + u3*g4.w);
        float step = 1.0f / (2.0f * lm + 1e-12f);
        step2 = 2.0f * step;
        wa = wb = wc = wd = 1.0f / 256.0f;    // project(uniform) = uniform (tau=0)
        ya = yb = yc = yd = 1.0f / 256.0f;
        *(float4*)(y_lds + 4 * tid) = make_float4(ya, yb, yc, yd);
    } else if (tid < 128) {
        *(float4*)(gb[pp ^ 1] + 4 * (tid - 64)) = make_float4(0.f, 0.f, 0.f, 0.f);
    }
    if (tid == 0) done_flag = 0;               // ordered by next B1
    pp ^= 1;

    // ---------------- Phase 3: FISTA ----------------
    for (int itn = 0; itn < 300; ++itn) {
        if (partials(gb[pp], true)) break;     // frozen-w early exit (uniform)
        if (tid < 64) {
            float4 g4 = *(const float4*)(gb[pp] + 4 * tid);
            float v0 = ya - step2 * g4.x;
            float v1 = yb - step2 * g4.y;
            float v2 = yc - step2 * g4.z;
            float v3 = yd - step2 * g4.w;

            // constant safeguard bracket: |v|inf <= ~1.5 so s(-2)>1>s(2) always
            float lo = -2.0f, hi = 2.0f;
            // extrapolated warm start (tau moves smoothly across FISTA iters)
            float tau = fminf(fmaxf(tau_ws + (tau_ws - tau_pv), lo), hi);

            float s = 0.f, cnt = 1.f, sm1 = 0.f;
            bool have = false;
            for (int ni = 0; ni < 10; ++ni) {
                float z0 = v0 - tau, z1 = v1 - tau, z2 = v2 - tau, z3 = v3 - tau;
                float c0 = fminf(fmaxf(z0, -CAPW), CAPW);
                float c1 = fminf(fmaxf(z1, -CAPW), CAPW);
                float c2 = fminf(fmaxf(z2, -CAPW), CAPW);
                float c3 = fminf(fmaxf(z3, -CAPW), CAPW);
                s   = wsum(c0 + c1 + c2 + c3);
                cnt = wsum((fabsf(z0) < CAPW ? 1.f : 0.f) +
                           (fabsf(z1) < CAPW ? 1.f : 0.f) +
                           (fabsf(z2) < CAPW ? 1.f : 0.f) +
                           (fabsf(z3) < CAPW ? 1.f : 0.f));
                sm1 = s - 1.0f;
                if (fabsf(sm1) <= 1e-4f) { have = true; break; }   // wave-uniform
                if (sm1 > 0.0f) lo = tau; else hi = tau;
                float tn2 = tau + sm1 / fmaxf(cnt, 1.0f);   // Newton: s' = -n_int
                if (!(tn2 > lo && tn2 < hi)) tn2 = 0.5f * (lo + hi);
                tau = tn2;
            }
            if (!have) {   // bound-exit: re-eval (s,cnt) at final tau
                float z0 = v0 - tau, z1 = v1 - tau, z2 = v2 - tau, z3 = v3 - tau;
                float c0 = fminf(fmaxf(z0, -CAPW), CAPW);
                float c1 = fminf(fmaxf(z1, -CAPW), CAPW);
                float c2 = fminf(fmaxf(z2, -CAPW), CAPW);
                float c3 = fminf(fmaxf(z3, -CAPW), CAPW);
                s   = wsum(c0 + c1 + c2 + c3);
                cnt = wsum((fabsf(z0) < CAPW ? 1.f : 0.f) +
                           (fabsf(z1) < CAPW ? 1.f : 0.f) +
                           (fabsf(z2) < CAPW ? 1.f : 0.f) +
                           (fabsf(z3) < CAPW ? 1.f : 0.f));
                sm1 = s - 1.0f;
            }
            // exact active-set tau == one Newton step from converged point
            float tauf = tau + sm1 / fmaxf(cnt, 1.0f);
            tau_pv = tau_ws;
            tau_ws = tauf;
            float w0n = fminf(fmaxf(v0 - tauf, -CAPW), CAPW);
            float w1n = fminf(fmaxf(v1 - tauf, -CAPW), CAPW);
            float w2n = fminf(fmaxf(v2 - tauf, -CAPW), CAPW);
            float w3n = fminf(fmaxf(v3 - tauf, -CAPW), CAPW);

            float tn = 0.5f * (1.0f + sqrtf(1.0f + 4.0f * t * t));
            float beta = (t - 1.0f) / tn;
            float y0n = w0n + beta * (w0n - wa);
            float y1n = w1n + beta * (w1n - wb);
            float y2n = w2n + beta * (w2n - wc);
            float y3n = w3n + beta * (w3n - wd);

            // publish y FIRST (earlier handoff), then bookkeeping
            *(float4*)(y_lds + 4 * tid) = make_float4(y0n, y1n, y2n, y3n);

            // frozen-w detection (8-iter window)
            float dm = fmaxf(fmaxf(fabsf(w0n - wa), fabsf(w1n - wb)),
                             fmaxf(fabsf(w2n - wc), fabsf(w3n - wd)));
            rm = fmaxf(rm, dm);
            if ((itn & 7) == 7) {
                float rmax = wmax(rm);
                if (rmax < 1e-7f && tid == 0) done_flag = 1;
                rm = 0.0f;
            }

            wa = w0n; wb = w1n; wc = w2n; wd = w3n;
            ya = y0n; yb = y1n; yc = y2n; yd = y3n;
            t = tn;
        } else if (tid < 128) {   // wave1: re-zero the idle buffer
            *(float4*)(gb[pp ^ 1] + 4 * (tid - 64)) = make_float4(0.f, 0.f, 0.f, 0.f);
        }
        pp ^= 1;
    }

    if (tid < 64) {
        *(float4*)(out + b * 256 + 4 * tid) = make_float4(wa, wb, wc, wd);
    }
}

extern "C" void kernel_launch(void* const* d_in, const int* in_sizes, int n_in,
                              void* d_out, int out_size, void* d_ws, size_t ws_size,
                              hipStream_t stream) {
    (void)in_sizes; (void)n_in; (void)d_ws; (void)ws_size; (void)out_size;
    const float* A = (const float*)d_in[0];
    float* out = (float*)d_out;
    hipLaunchKernelGGL(markowitz_fista, dim3(512), dim3(512), 0, stream, A, out);
}

// Round 5
// 933.891 us; speedup vs baseline: 2.6739x; 2.6739x over previous
//
#include <hip/hip_runtime.h>
#include <math.h>

// Markowitz min-variance via FISTA, one block (512 thr, 8 waves) per problem.
// Q register-resident: thread (r4=tid&63, e=tid>>6) owns Q[4*r4..+3][32*e..+31].
// R7: R5 structure restored (p_lds partials + wave0 reduceg — R6's LDS float
// atomics were a contended-RMW disaster, 3x slower). Changes vs R5:
//  - SECANT root loop: one wsum (s) per trip; slope from consecutive evals
//    (piecewise-linear s => secant slope == -interior_count of the piece);
//    first-trip slope = cached cnt from previous FISTA iter. cnt wsum done
//    ONCE after convergence for the exact active-set step (same semantics).
//  - normalization-free power iteration: exact x0.25 scaling per iter
//    (pow2 => exact, direction-preserving; lambda_max ~= 4 keeps |u| sane);
//    Rayleigh at end as wsum(u.g)/wsum(u.u).
//  - kept from R5/R6: const bracket [-2,2], extrapolated tau warm start,
//    Newton tol 1e-4, frozen-w exit 1e-7 (8-iter window), publish-y-first.

#define NA    256
#define CAPW  0.05f

typedef float v2f __attribute__((ext_vector_type(2)));

// ---- DPP wave-64 reductions ----
template<int CTRL, int RM>
__device__ __forceinline__ float dpp0(float x) {      // old = 0, bound_ctrl = true
    return __int_as_float(__builtin_amdgcn_update_dpp(
        0, __float_as_int(x), CTRL, RM, 0xf, true));
}
template<int CTRL, int RM>
__device__ __forceinline__ float dppI(float x, float ident) { // old = ident
    return __int_as_float(__builtin_amdgcn_update_dpp(
        __float_as_int(ident), __float_as_int(x), CTRL, RM, 0xf, false));
}
__device__ __forceinline__ float bcast63(float x) {
    return __int_as_float(__builtin_amdgcn_readlane(__float_as_int(x), 63));
}
__device__ __forceinline__ float wsum(float x) {
    x += dpp0<0x111, 0xf>(x);   // row_shr:1
    x += dpp0<0x112, 0xf>(x);   // row_shr:2
    x += dpp0<0x114, 0xf>(x);   // row_shr:4
    x += dpp0<0x118, 0xf>(x);   // row_shr:8
    x += dpp0<0x142, 0xa>(x);   // row_bcast:15 -> rows 1,3
    x += dpp0<0x143, 0xc>(x);   // row_bcast:31 -> rows 2,3
    return bcast63(x);
}
__device__ __forceinline__ float wmax(float x) {
    const float I = -1e30f;
    x = fmaxf(x, dppI<0x111, 0xf>(x, I));
    x = fmaxf(x, dppI<0x112, 0xf>(x, I));
    x = fmaxf(x, dppI<0x114, 0xf>(x, I));
    x = fmaxf(x, dppI<0x118, 0xf>(x, I));
    x = fmaxf(x, dppI<0x142, 0xa>(x, I));
    x = fmaxf(x, dppI<0x143, 0xc>(x, I));
    return bcast63(x);
}

__global__ void __launch_bounds__(512, 2)
markowitz_fista(const float* __restrict__ A, float* __restrict__ out)
{
    // 32KB pool: phase 1 uses all of it as A staging; afterwards the first
    // 8KB are the matvec partials and the next 1KB is the published y vector.
    __shared__ float lds_pool[32 * 256];
    __shared__ int   done_flag;

    float* A_lds = lds_pool;            // [32*256] during phase 1 only
    float* p_lds = lds_pool;            // [8][256] partials, after phase 1
    float* y_lds = lds_pool + 2048;     // [256] published y, after phase 1

    const int tid = threadIdx.x;
    const int b   = blockIdx.x;
    const int r4  = tid & 63;
    const int e   = tid >> 6;           // wave id == col-chunk
    const int R0  = r4 * 4;
    const int C0  = e * 32;

    const float* __restrict__ Ab = A + (size_t)b * NA * NA;

    // ---------------- Phase 1: Q = A^T A into registers (packed fp32) -------
    v2f q2[4][16];
    #pragma unroll
    for (int a = 0; a < 4; ++a)
        #pragma unroll
        for (int k = 0; k < 16; ++k) q2[a][k] = (v2f){0.0f, 0.0f};

    for (int it = 0; it < 8; ++it) {
        __syncthreads();
        const float4* src = (const float4*)(Ab + it * 32 * 256);
        float4* dst = (float4*)A_lds;
        #pragma unroll
        for (int qd = 0; qd < 4; ++qd) dst[qd * 512 + tid] = src[qd * 512 + tid];
        __syncthreads();
        for (int ii = 0; ii < 32; ++ii) {
            const float* row = A_lds + ii * 256;
            float4 rv = *(const float4*)(row + R0);
            v2f r0 = {rv.x, rv.x}, r1 = {rv.y, rv.y}, r2 = {rv.z, rv.z}, r3 = {rv.w, rv.w};
            #pragma unroll
            for (int cc = 0; cc < 8; ++cc) {
                float4 cv = *(const float4*)(row + C0 + 4 * cc);
                v2f clo = {cv.x, cv.y}, chi = {cv.z, cv.w};
                q2[0][2*cc  ] = __builtin_elementwise_fma(r0, clo, q2[0][2*cc  ]);
                q2[0][2*cc+1] = __builtin_elementwise_fma(r0, chi, q2[0][2*cc+1]);
                q2[1][2*cc  ] = __builtin_elementwise_fma(r1, clo, q2[1][2*cc  ]);
                q2[1][2*cc+1] = __builtin_elementwise_fma(r1, chi, q2[1][2*cc+1]);
                q2[2][2*cc  ] = __builtin_elementwise_fma(r2, clo, q2[2][2*cc  ]);
                q2[2][2*cc+1] = __builtin_elementwise_fma(r2, chi, q2[2][2*cc+1]);
                q2[3][2*cc  ] = __builtin_elementwise_fma(r3, clo, q2[3][2*cc  ]);
                q2[3][2*cc+1] = __builtin_elementwise_fma(r3, chi, q2[3][2*cc+1]);
            }
        }
    }
    __syncthreads();   // alias safety: all A_lds reads done before p/y reuse

    // all waves: partials of Q*y_lds into p_lds.  Returns true on early-exit
    // (flag read is issued first and hidden behind the matvec FMAs).
    auto partials = [&](bool chk) -> bool {
        __syncthreads();                               // B1: y_lds / flag visible
        int fl = chk ? done_flag : 0;
        v2f aL0 = {0,0}, aL1 = {0,0}, aL2 = {0,0}, aL3 = {0,0};
        v2f aH0 = {0,0}, aH1 = {0,0}, aH2 = {0,0}, aH3 = {0,0};
        const float* yv = y_lds + C0;
        #pragma unroll
        for (int cc = 0; cc < 8; ++cc) {
            float4 y4 = *(const float4*)(yv + 4 * cc);
            v2f ylo = {y4.x, y4.y}, yhi = {y4.z, y4.w};
            aL0 = __builtin_elementwise_fma(q2[0][2*cc  ], ylo, aL0);
            aH0 = __builtin_elementwise_fma(q2[0][2*cc+1], yhi, aH0);
            aL1 = __builtin_elementwise_fma(q2[1][2*cc  ], ylo, aL1);
            aH1 = __builtin_elementwise_fma(q2[1][2*cc+1], yhi, aH1);
            aL2 = __builtin_elementwise_fma(q2[2][2*cc  ], ylo, aL2);
            aH2 = __builtin_elementwise_fma(q2[2][2*cc+1], yhi, aH2);
            aL3 = __builtin_elementwise_fma(q2[3][2*cc  ], ylo, aL3);
            aH3 = __builtin_elementwise_fma(q2[3][2*cc+1], yhi, aH3);
        }
        if (fl) return true;                           // block-uniform
        v2f s0 = aL0 + aH0, s1 = aL1 + aH1, s2 = aL2 + aH2, s3 = aL3 + aH3;
        *(float4*)(p_lds + e * 256 + R0) =
            make_float4(s0.x + s0.y, s1.x + s1.y, s2.x + s2.y, s3.x + s3.y);
        __syncthreads();                               // B2: p_lds visible
        return false;
    };
    // wave0 (tid<64): reduce the 8 partials for rows 4*tid..4*tid+3
    auto reduceg = [&]() -> float4 {
        float4 r = *(const float4*)(p_lds + 4 * tid);
        #pragma unroll
        for (int ee = 1; ee < 8; ++ee) {
            float4 pv = *(const float4*)(p_lds + ee * 256 + 4 * tid);
            r.x += pv.x; r.y += pv.y; r.z += pv.z; r.w += pv.w;
        }
        return r;
    };

    // ---------------- Phase 2: power iteration for step size ----------------
    // Normalization-free: u_{k+1} = 0.25 * Q u_k (exact pow2 scaling preserves
    // direction exactly; lambda_max ~= 4 keeps magnitudes in fp32 range).
    if (tid < 64) {
        *(float4*)(y_lds + 4 * tid) = make_float4(0.0625f, 0.0625f, 0.0625f, 0.0625f);
    }
    float u0 = 0.0625f, u1 = 0.0625f, u2 = 0.0625f, u3 = 0.0625f;
    for (int p = 0; p < 30; ++p) {
        partials(false);
        if (tid < 64) {
            float4 g4 = reduceg();
            u0 = 0.25f * g4.x; u1 = 0.25f * g4.y;
            u2 = 0.25f * g4.z; u3 = 0.25f * g4.w;
            *(float4*)(y_lds + 4 * tid) = make_float4(u0, u1, u2, u3);
        }
    }
    partials(false);   // Q*u for Rayleigh quotient

    float step2 = 0.f, t = 1.0f, tau_ws = 0.0f, tau_pv = 0.0f, rm = 0.0f;
    float cnt_ws = 256.0f;   // interior count cache (slope seed), all-interior at start
    float wa = 0.f, wb = 0.f, wc = 0.f, wd = 0.f;
    float ya = 0.f, yb = 0.f, yc = 0.f, yd = 0.f;
    if (tid < 64) {
        float4 g4 = reduceg();
        // Rayleigh on unnormalized u: (u.g)/(u.u)  — two interleaved wsum chains
        float num = wsum(u0*g4.x + u1*g4.y + u2*g4.z + u3*g4.w);
        float den = wsum(u0*u0 + u1*u1 + u2*u2 + u3*u3);
        float lm = num / (den + 1e-30f);
        float step = 1.0f / (2.0f * lm + 1e-12f);
        step2 = 2.0f * step;
        wa = wb = wc = wd = 1.0f / 256.0f;    // project(uniform) = uniform (tau=0)
        ya = yb = yc = yd = 1.0f / 256.0f;
        *(float4*)(y_lds + 4 * tid) = make_float4(ya, yb, yc, yd);
    }
    if (tid == 0) done_flag = 0;               // ordered by next B1

    // ---------------- Phase 3: FISTA ----------------
    for (int itn = 0; itn < 300; ++itn) {
        if (partials(true)) break;             // frozen-w early exit (uniform)
        if (tid < 64) {
            float4 g4 = reduceg();
            float v0 = ya - step2 * g4.x;
            float v1 = yb - step2 * g4.y;
            float v2 = yc - step2 * g4.z;
            float v3 = yd - step2 * g4.w;

            // constant safeguard bracket: |v|inf <= ~1.5 so s(-2)>1>s(2) always
            float lo = -2.0f, hi = 2.0f;
            // extrapolated warm start (tau moves smoothly across FISTA iters)
            float tau = fminf(fmaxf(tau_ws + (tau_ws - tau_pv), lo), hi);

            // SECANT loop: one wsum (s) per trip; slope from consecutive evals
            // (s is piecewise-linear with slope = -interior_count), seeded by
            // the previous FISTA iteration's interior count.
            float s = 0.f, sm1 = 0.f;
            float tau_p = 0.f, s_p = 0.f;
            bool havep = false, have = false;
            for (int ni = 0; ni < 10; ++ni) {
                float z0 = v0 - tau, z1 = v1 - tau, z2 = v2 - tau, z3 = v3 - tau;
                float c0 = fminf(fmaxf(z0, -CAPW), CAPW);
                float c1 = fminf(fmaxf(z1, -CAPW), CAPW);
                float c2 = fminf(fmaxf(z2, -CAPW), CAPW);
                float c3 = fminf(fmaxf(z3, -CAPW), CAPW);
                s = wsum((c0 + c1) + (c2 + c3));
                sm1 = s - 1.0f;
                if (fabsf(sm1) <= 1e-4f) { have = true; break; }   // wave-uniform
                if (sm1 > 0.0f) lo = tau; else hi = tau;
                float m = fmaxf(cnt_ws, 1.0f);
                if (havep) {
                    float dt = tau - tau_p;
                    float ds = s_p - s;            // >= 0 when dt > 0 (s decreasing)
                    float mm = ds / dt;            // piece slope magnitude
                    if (mm > 0.5f && mm == mm) m = mm;   // guard degenerate/NaN
                }
                float tn2 = tau + sm1 / m;
                if (!(tn2 > lo && tn2 < hi)) tn2 = 0.5f * (lo + hi);
                tau_p = tau; s_p = s; havep = true;
                tau = tn2;
            }
            if (!have) {   // bound-exit: re-eval s at final tau
                float z0 = v0 - tau, z1 = v1 - tau, z2 = v2 - tau, z3 = v3 - tau;
                float c0 = fminf(fmaxf(z0, -CAPW), CAPW);
                float c1 = fminf(fmaxf(z1, -CAPW), CAPW);
                float c2 = fminf(fmaxf(z2, -CAPW), CAPW);
                float c3 = fminf(fmaxf(z3, -CAPW), CAPW);
                s = wsum((c0 + c1) + (c2 + c3));
                sm1 = s - 1.0f;
            }
            // exact active-set tau == one Newton step with the exact interior
            // count at the converged tau (single cnt wsum per FISTA iter)
            {
                float z0 = v0 - tau, z1 = v1 - tau, z2 = v2 - tau, z3 = v3 - tau;
                float cnt = wsum((fabsf(z0) < CAPW ? 1.f : 0.f) +
                                 (fabsf(z1) < CAPW ? 1.f : 0.f) +
                                 (fabsf(z2) < CAPW ? 1.f : 0.f) +
                                 (fabsf(z3) < CAPW ? 1.f : 0.f));
                cnt_ws = cnt;
                tau = tau + sm1 / fmaxf(cnt, 1.0f);
            }
            tau_pv = tau_ws;
            tau_ws = tau;
            float w0n = fminf(fmaxf(v0 - tau, -CAPW), CAPW);
            float w1n = fminf(fmaxf(v1 - tau, -CAPW), CAPW);
            float w2n = fminf(fmaxf(v2 - tau, -CAPW), CAPW);
            float w3n = fminf(fmaxf(v3 - tau, -CAPW), CAPW);

            float tn = 0.5f * (1.0f + sqrtf(1.0f + 4.0f * t * t));
            float beta = (t - 1.0f) / tn;
            float y0n = w0n + beta * (w0n - wa);
            float y1n = w1n + beta * (w1n - wb);
            float y2n = w2n + beta * (w2n - wc);
            float y3n = w3n + beta * (w3n - wd);

            // publish y FIRST (earlier handoff), then bookkeeping
            *(float4*)(y_lds + 4 * tid) = make_float4(y0n, y1n, y2n, y3n);

            // frozen-w detection (8-iter window)
            float dm = fmaxf(fmaxf(fabsf(w0n - wa), fabsf(w1n - wb)),
                             fmaxf(fabsf(w2n - wc), fabsf(w3n - wd)));
            rm = fmaxf(rm, dm);
            if ((itn & 7) == 7) {
                float rmax = wmax(rm);
                if (rmax < 1e-7f && tid == 0) done_flag = 1;
                rm = 0.0f;
            }

            wa = w0n; wb = w1n; wc = w2n; wd = w3n;
            ya = y0n; yb = y1n; yc = y2n; yd = y3n;
            t = tn;
        }
    }

    if (tid < 64) {
        *(float4*)(out + b * 256 + 4 * tid) = make_float4(wa, wb, wc, wd);
    }
}

extern "C" void kernel_launch(void* const* d_in, const int* in_sizes, int n_in,
                              void* d_out, int out_size, void* d_ws, size_t ws_size,
                              hipStream_t stream) {
    (void)in_sizes; (void)n_in; (void)d_ws; (void)ws_size; (void)out_size;
    const float* A = (const float*)d_in[0];
    float* out = (float*)d_out;
    hipLaunchKernelGGL(markowitz_fista, dim3(512), dim3(512), 0, stream, A, out);
}